// Round 10
// baseline (957.233 us; speedup 1.0000x reference)
//
#include <hip/hip_runtime.h>

#define DDIM 80
#define PLANE 6400
#define VOL 512000
#define HALFV 4
#define NVOL 8
#define NTOT (NVOL*VOL)
#define NCH 20          // float4 chunks per 80-float row
#define RP 84           // padded row floats in rings

// ---------------- pair-kernel (2 fused iterations) ----------------
#define PTY 10          // output rows per tile
#define PCZ 10          // output slices per tile
#define PE1R 14         // E1 rows (y-halo 2 per side)
#define PHR 12          // H1/E2/H2 rows (y-halo 1 per side)
#define PBLK 320
#define PGRID 512       // 8 vols x 8 yt x 8 zc -> exactly 2 blocks/CU

// ---------------- last-iter kernel (R7 shape) ----------------
#define STY 10
#define SCZ 5
#define SER (STY + 2)
#define SBLK 256
#define SGRID 1024      // 8 vols x 8 yt x 16 zc

__device__ __forceinline__ float4 f4min(float4 a, float4 b) {
    return make_float4(fminf(a.x,b.x), fminf(a.y,b.y), fminf(a.z,b.z), fminf(a.w,b.w));
}
__device__ __forceinline__ float4 f4max(float4 a, float4 b) {
    return make_float4(fmaxf(a.x,b.x), fmaxf(a.y,b.y), fmaxf(a.z,b.z), fmaxf(a.w,b.w));
}
__device__ __forceinline__ int s4(int v){ return (v + 8) & 3; }   // v >= -8
__device__ __forceinline__ int s2(int v){ return (v + 8) & 1; }
__device__ __forceinline__ float updf(float s, float d){ return s + fmaxf(d - s*d, 0.0f); }

// LDS-only barrier (does not drain vmcnt)
__device__ __forceinline__ void lbar() {
    asm volatile("s_waitcnt lgkmcnt(0)\n\ts_barrier" ::: "memory");
}

struct EIn { float4 c, zA, zB, yA, yB; float lf, rt; };

// ======================= pair kernel: iters 2j, 2j+1 =======================
template<bool FIRST>
__global__ __launch_bounds__(PBLK, 2) void pair_k(const float* __restrict__ xin,
                                                  const float* __restrict__ yin,
                                                  const float* __restrict__ a,
                                                  float* __restrict__ eout,
                                                  float* __restrict__ skel)
{
    __shared__ float E1[4][PE1R][RP];   // 18816 B
    __shared__ float H1[4][PHR][RP];    // 16128 B
    __shared__ float E2[2][PHR][RP];    //  8064 B
    __shared__ float H2[4][PHR][RP];    // 16128 B  (total 59136 B -> 2 blocks/CU)

    const int b = blockIdx.x;
    const int v   = b >> 6;          // volume 0..7
    const int rem = b & 63;
    const int yt  = rem >> 3;        // 0..7
    const int zci = rem & 7;         // 0..7
    const int y0 = yt*PTY;
    const int z0 = zci*PCZ;

    const float* __restrict__ src =
        FIRST ? ((v < HALFV) ? (xin + v*VOL) : (yin + (v-HALFV)*VOL)) : (a + v*VOL);
    float* __restrict__ ev  = eout + v*VOL;
    float* __restrict__ skv = skel + v*VOL;

    const int tid = threadIdx.x;
    const int r = tid / NCH;         // 0..15 (E1 valid r<14, H/E2 r<12, upd r<10)
    const int c = tid - r*NCH;       // 0..19
    const int x4 = 4*c;

    auto loadE1 = [&](int zs, EIn& e) {
        if (r < PE1R) {
            const int gy  = y0 - 2 + r;
            const int gyc = min(max(gy, 0), DDIM-1);
            const int zcl = min(max(zs, 0), DDIM-1);
            const int zm = max(zcl-1, 0), zp = min(zcl+1, DDIM-1);
            const int ym = max(gyc-1, 0), yp = min(gyc+1, DDIM-1);
            const float* rc = src + zcl*PLANE + gyc*DDIM;
            e.c  = *(const float4*)(rc + x4);
            e.lf = rc[max(x4-1, 0)];
            e.rt = rc[min(x4+4, DDIM-1)];
            e.zA = *(const float4*)(src + zm*PLANE + gyc*DDIM + x4);
            e.zB = *(const float4*)(src + zp*PLANE + gyc*DDIM + x4);
            e.yA = *(const float4*)(src + zcl*PLANE + ym*DDIM + x4);
            e.yB = *(const float4*)(src + zcl*PLANE + yp*DDIM + x4);
        }
    };

    auto erodeC = [&](const EIn& e) -> float4 {
        float4 m;
        m.x = fminf(fminf(e.lf,  e.c.x), e.c.y);
        m.y = fminf(fminf(e.c.x, e.c.y), e.c.z);
        m.z = fminf(fminf(e.c.y, e.c.z), e.c.w);
        m.w = fminf(fminf(e.c.z, e.c.w), e.rt);
        return f4min(m, f4min(f4min(e.zA, e.zB), f4min(e.yA, e.yB)));
    };

    auto storeE1 = [&](int zs, float4 m) {
        if (r < PE1R) *(float4*)&E1[s4(zs)][r][x4] = m;
    };

    auto hmax1 = [&](int zs) {
        if (r < PHR) {
            const float* row = &E1[s4(zs)][r+1][0];
            const float4 f = *(const float4*)(row + x4);
            const float lf = (c>0)  ? row[x4-1] : f.x;
            const float rt = (c<19) ? row[x4+4] : f.w;
            float4 h;
            h.x = fmaxf(fmaxf(lf,  f.x), f.y);
            h.y = fmaxf(fmaxf(f.x, f.y), f.z);
            h.z = fmaxf(fmaxf(f.y, f.z), f.w);
            h.w = fmaxf(fmaxf(f.z, f.w), rt);
            *(float4*)&H1[s4(zs)][r][x4] = h;
        }
    };

    auto erode2 = [&](int zs, bool gw) {
        if (r < PHR) {
            const float* rc = &E1[s4(zs)][r+1][0];
            const float4 cc = *(const float4*)(rc + x4);
            const float lf = (c>0)  ? rc[x4-1] : cc.x;
            const float rt = (c<19) ? rc[x4+4] : cc.w;
            float4 m;
            m.x = fminf(fminf(lf,   cc.x), cc.y);
            m.y = fminf(fminf(cc.x, cc.y), cc.z);
            m.z = fminf(fminf(cc.y, cc.z), cc.w);
            m.w = fminf(fminf(cc.z, cc.w), rt);
            m = f4min(m, *(const float4*)&E1[s4(zs)][r][x4]);
            m = f4min(m, *(const float4*)&E1[s4(zs)][r+2][x4]);
            m = f4min(m, *(const float4*)&E1[s4(zs-1)][r+1][x4]);
            m = f4min(m, *(const float4*)&E1[s4(zs+1)][r+1][x4]);
            *(float4*)&E2[s2(zs)][r][x4] = m;
            if (gw && r >= 1 && r <= PTY)
                *(float4*)(ev + zs*PLANE + (y0-1+r)*DDIM + x4) = m;
        }
    };

    auto hmax2 = [&](int zs) {
        if (r < PHR) {
            const float* row = &E2[s2(zs)][r][0];
            const float4 f = *(const float4*)(row + x4);
            const float lf = (c>0)  ? row[x4-1] : f.x;
            const float rt = (c<19) ? row[x4+4] : f.w;
            float4 h;
            h.x = fmaxf(fmaxf(lf,  f.x), f.y);
            h.y = fmaxf(fmaxf(f.x, f.y), f.z);
            h.z = fmaxf(fmaxf(f.y, f.z), f.w);
            h.w = fmaxf(fmaxf(f.z, f.w), rt);
            *(float4*)&H2[s4(zs)][r][x4] = h;
        }
    };

    auto loadD1 = [&](int z, float4& img, float4& sk) {
        if (r < PTY) {
            const int off = z*PLANE + (y0 + r)*DDIM + x4;
            img = *(const float4*)(src + off);
            if constexpr (!FIRST) sk = *(const float4*)(skv + off);
        }
    };

    EIn eS0, eS1;
    float4 img2N = make_float4(0,0,0,0), img2P = make_float4(0,0,0,0);
    float4 skA = make_float4(0,0,0,0), skB = skA, skC = skA;
    float4 dImg = skA, dSk = skA;

    // ---- prologue ----
    loadE1(z0-2, eS0);
    loadE1(z0-1, eS1);
    storeE1(z0-2, erodeC(eS0));
    storeE1(z0-1, erodeC(eS1));
    loadE1(z0,   eS0);
    loadE1(z0+1, eS1);
    lbar();
    storeE1(z0,   erodeC(eS0));
    storeE1(z0+1, erodeC(eS1));
    hmax1(z0-1);
    loadE1(z0+2, eS1);            // consumed at S=-1
    lbar();
    hmax1(z0);
    erode2(z0-1, false);
    loadE1(z0+3, eS0);            // consumed at S=0
    lbar();

    // ---- main loop: S = -1 .. PCZ, one light barrier per step ----
#pragma unroll
    for (int S = -1; S <= PCZ; ++S) {
        const int z = z0 + S;
        // ---------- phase A ----------
        if (S <= PCZ-2) {
            const float4 m = erodeC((S & 1) ? eS1 : eS0);
            storeE1(z+3, m);
        }
        if (S <= PCZ-4) loadE1(z+5, (S & 1) ? eS1 : eS0);
        if (S <= PCZ-2) hmax1(z+2);
        if (S <= PCZ-1) erode2(z+1, S <= PCZ-2);
        hmax2(z);
        if (S >= 0 && S <= PCZ-1) {
            if (r < PTY) img2N = *(const float4*)&E1[s4(z)][r+2][x4];
        }
        if (S <= PCZ-2) loadD1(z+1, dImg, dSk);
        lbar();
        // ---------- phase B ----------
        if (S <= PCZ-2) {          // upd1(z+1): iter 2j
            if (r < PTY) {
                float4 dm = make_float4(-1e30f, -1e30f, -1e30f, -1e30f);
#pragma unroll
                for (int s = 0; s < 3; ++s)
#pragma unroll
                    for (int l = 0; l < 3; ++l)
                        dm = f4max(dm, *(const float4*)&H1[s4(z+s)][r + l][x4]);
                float4 dl;
                dl.x = fmaxf(dImg.x - dm.x, 0.0f);
                dl.y = fmaxf(dImg.y - dm.y, 0.0f);
                dl.z = fmaxf(dImg.z - dm.z, 0.0f);
                dl.w = fmaxf(dImg.w - dm.w, 0.0f);
                if constexpr (FIRST) {
                    skC = dl;
                } else {
                    skC.x = updf(dSk.x, dl.x); skC.y = updf(dSk.y, dl.y);
                    skC.z = updf(dSk.z, dl.z); skC.w = updf(dSk.w, dl.w);
                }
            }
        }
        if (S >= 1) {              // upd2(z-1): iter 2j+1
            if (r < PTY) {
                float4 dm = make_float4(-1e30f, -1e30f, -1e30f, -1e30f);
#pragma unroll
                for (int s = 0; s < 3; ++s)
#pragma unroll
                    for (int l = 0; l < 3; ++l)
                        dm = f4max(dm, *(const float4*)&H2[s4(z-2+s)][r + l][x4]);
                float4 dl;
                dl.x = fmaxf(img2P.x - dm.x, 0.0f);
                dl.y = fmaxf(img2P.y - dm.y, 0.0f);
                dl.z = fmaxf(img2P.z - dm.z, 0.0f);
                dl.w = fmaxf(img2P.w - dm.w, 0.0f);
                float4 sf;
                sf.x = updf(skA.x, dl.x); sf.y = updf(skA.y, dl.y);
                sf.z = updf(skA.z, dl.z); sf.w = updf(skA.w, dl.w);
                *(float4*)(skv + (z-1)*PLANE + (y0 + r)*DDIM + x4) = sf;
            }
        }
        skA = skB; skB = skC;
        img2P = img2N;
    }
}

// ============ last iteration (iter 50) fused with the reduction ============
// Computes final skel values in registers; accumulates sa = sum(cnt*skel),
// sb = sum(skel) per block. No skel write, no separate reduce pass.
__global__ __launch_bounds__(SBLK, 4) void last_k(const float* __restrict__ xin,
                                                  const float* __restrict__ yin,
                                                  const float* __restrict__ a,
                                                  float* __restrict__ skel,
                                                  float* __restrict__ partials)
{
    __shared__ float E[3][SER][RP];
    __shared__ float H[4][SER][RP];
    __shared__ float smm[4][2];

    const int b = blockIdx.x;
    const int v   = b >> 7;          // volume 0..7 (128 blocks each)
    const int rem = b & 127;
    const int yt  = rem >> 4;
    const int zci = rem & 15;
    const int y0 = yt*STY;
    const int z0 = zci*SCZ;

    const float* __restrict__ src = a + v*VOL;
    const float* __restrict__ skv = skel + v*VOL;
    const float* __restrict__ cnt =
        (v < HALFV) ? (yin + v*VOL) : (xin + (v-HALFV)*VOL);

    const int tid = threadIdx.x;
    const int r = tid / NCH;
    const int c = tid - r*NCH;
    const int x4 = 4*c;

    auto slotE = [](int vv){ return (vv + 9) % 3; };

    auto loadE = [&](int zs, EIn& e) {
        if (tid < SER*NCH) {
            const int gy  = y0 - 1 + r;
            const int gyc = min(max(gy, 0), DDIM-1);
            const int zcl = min(max(zs, 0), DDIM-1);
            const int zm = max(zcl-1, 0), zp = min(zcl+1, DDIM-1);
            const int ym = max(gyc-1, 0), yp = min(gyc+1, DDIM-1);
            const float* rc = src + zcl*PLANE + gyc*DDIM;
            e.c  = *(const float4*)(rc + x4);
            e.lf = rc[max(x4-1, 0)];
            e.rt = rc[min(x4+4, DDIM-1)];
            e.zA = *(const float4*)(src + zm*PLANE + gyc*DDIM + x4);
            e.zB = *(const float4*)(src + zp*PLANE + gyc*DDIM + x4);
            e.yA = *(const float4*)(src + zcl*PLANE + ym*DDIM + x4);
            e.yB = *(const float4*)(src + zcl*PLANE + yp*DDIM + x4);
        }
    };
    auto erodeC = [&](const EIn& e) -> float4 {
        float4 m;
        m.x = fminf(fminf(e.lf,  e.c.x), e.c.y);
        m.y = fminf(fminf(e.c.x, e.c.y), e.c.z);
        m.z = fminf(fminf(e.c.y, e.c.z), e.c.w);
        m.w = fminf(fminf(e.c.z, e.c.w), e.rt);
        return f4min(m, f4min(f4min(e.zA, e.zB), f4min(e.yA, e.yB)));
    };
    auto storeE = [&](int zs, const float4& m) {
        if (tid < SER*NCH) *(float4*)&E[slotE(zs)][r][x4] = m;
    };
    auto hmaxStore = [&](int zs, const float4& m) {
        if (tid < SER*NCH) {
            const float* er = &E[slotE(zs)][r][0];
            const float lf = (c > 0)  ? er[x4-1] : m.x;
            const float rt = (c < 19) ? er[x4+4] : m.w;
            float4 h;
            h.x = fmaxf(fmaxf(lf,  m.x), m.y);
            h.y = fmaxf(fmaxf(m.x, m.y), m.z);
            h.z = fmaxf(fmaxf(m.y, m.z), m.w);
            h.w = fmaxf(fmaxf(m.z, m.w), rt);
            *(float4*)&H[s4(zs)][r][x4] = h;
        }
    };
    auto loadD = [&](int z, float4& img, float4& sk, float4& cv) {
        if (tid < STY*NCH) {
            const int off = z*PLANE + (y0 + r)*DDIM + x4;
            img = *(const float4*)(src + off);
            sk  = *(const float4*)(skv + off);
            cv  = *(const float4*)(cnt + off);
        }
    };

    float sa = 0.0f, sb = 0.0f;

    auto dilateUpd = [&](int z, const float4& img, const float4& skin, const float4& cv) {
        if (tid < STY*NCH) {
            float4 dm = make_float4(-1e30f, -1e30f, -1e30f, -1e30f);
#pragma unroll
            for (int s = 0; s < 3; ++s)
#pragma unroll
                for (int l = 0; l < 3; ++l)
                    dm = f4max(dm, *(const float4*)&H[s4(z-1+s)][r + l][x4]);
            float4 dl;
            dl.x = fmaxf(img.x - dm.x, 0.0f);
            dl.y = fmaxf(img.y - dm.y, 0.0f);
            dl.z = fmaxf(img.z - dm.z, 0.0f);
            dl.w = fmaxf(img.w - dm.w, 0.0f);
            float4 s;
            s.x = updf(skin.x, dl.x); s.y = updf(skin.y, dl.y);
            s.z = updf(skin.z, dl.z); s.w = updf(skin.w, dl.w);
            sa += cv.x*s.x + cv.y*s.y + cv.z*s.z + cv.w*s.w;
            sb += s.x + s.y + s.z + s.w;
        }
    };

    EIn eP, eQ, eR;
    float4 m0, m1, m2, mPrev, mNew;
    float4 dImg, dSk, dCv, dImgN, dSkN, dCvN;

    loadE(z0-1, eP);
    loadE(z0,   eQ);
    loadE(z0+1, eR);
    m0 = erodeC(eP);  storeE(z0-1, m0);
    m1 = erodeC(eQ);  storeE(z0,   m1);
    lbar();
    loadE(z0+2, eP);
    loadE(z0+3, eQ);
    hmaxStore(z0-1, m0);
    hmaxStore(z0,   m1);
    m2 = erodeC(eR);  storeE(z0+1, m2);
    loadD(z0, dImg, dSk, dCv);
    lbar();
    mPrev = m2;

#pragma unroll
    for (int S = 0; S < SCZ; ++S) {
        const int z = z0 + S;
        if (S <= SCZ-2) {
            mNew = erodeC((S & 1) ? eQ : eP);
            storeE(z+2, mNew);
        }
        if (S <= SCZ-4) loadE(z+4, (S & 1) ? eQ : eP);
        hmaxStore(z+1, mPrev);
        if (S <= SCZ-2) loadD(z+1, dImgN, dSkN, dCvN);
        lbar();
        dilateUpd(z, dImg, dSk, dCv);
        if (S <= SCZ-2) { mPrev = mNew; dImg = dImgN; dSk = dSkN; dCv = dCvN; }
    }

    // block reduction
    for (int off = 32; off > 0; off >>= 1) {
        sa += __shfl_down(sa, off);
        sb += __shfl_down(sb, off);
    }
    const int wave = tid >> 6;
    if ((tid & 63) == 0) { smm[wave][0] = sa; smm[wave][1] = sb; }
    __syncthreads();
    if (tid == 0) {
        float a0 = 0, a1 = 0;
        for (int w = 0; w < 4; ++w) { a0 += smm[w][0]; a1 += smm[w][1]; }
        partials[b*2 + 0] = a0;
        partials[b*2 + 1] = a1;
    }
}

__global__ void final_k(const float* __restrict__ p, float* __restrict__ out) {
    __shared__ float sums[16];
    const int t = threadIdx.x;
    if (t < 16) {
        const int vv = t >> 1, k = t & 1;
        float acc = 0.0f;
        for (int j = 0; j < 128; ++j) acc += p[(vv*128 + j)*2 + k];
        sums[t] = acc;
    }
    __syncthreads();
    if (t == 0) {
        float acc = 0.0f;
        for (int ch = 0; ch < 4; ++ch) {
            const float tpc     = sums[ch*2 + 0];        // sum clp*y
            const float sum_clp = sums[ch*2 + 1];        // sum clp
            const float tp      = sums[(4+ch)*2 + 0];    // sum x*cll
            const float sum_cll = sums[(4+ch)*2 + 1];    // sum cll
            const float fn  = sum_cll - tp;
            const float fpc = sum_clp - tpc;
            const float clp2voll = (tpc + 1.0f) / (tpc + fpc + 1.0f);
            const float cll2volp = (tp + 1.0f) / (tp + fn + 1.0f);
            acc += 2.0f * clp2voll * cll2volp / (cll2volp + clp2voll + 1e-8f);
        }
        out[0] = 1.0f - acc * 0.25f;
    }
}

extern "C" void kernel_launch(void* const* d_in, const int* in_sizes, int n_in,
                              void* d_out, int out_size, void* d_ws, size_t ws_size,
                              hipStream_t stream) {
    const float* x = (const float*)d_in[0];
    const float* y = (const float*)d_in[1];
    float* out = (float*)d_out;

    float* bufA = (float*)d_ws;
    float* bufB = bufA + NTOT;
    float* skel = bufB + NTOT;
    float* partials = skel + NTOT;   // 2048 floats

    // pair 0: iterations 0,1 (src = inputs) -> bufA holds e^2
    pair_k<true><<<PGRID, PBLK, 0, stream>>>(x, y, nullptr, bufA, skel);
    // pairs 1..24: iterations 2j, 2j+1
    for (int j = 1; j <= 24; ++j) {
        float* srcb = (j & 1) ? bufA : bufB;
        float* dstb = (j & 1) ? bufB : bufA;
        pair_k<false><<<PGRID, PBLK, 0, stream>>>(nullptr, nullptr, srcb, dstb, skel);
    }
    // iteration 50 fused with reduction (reads e^50 in bufA, skel, counterpart input)
    last_k<<<SGRID, SBLK, 0, stream>>>(x, y, bufA, skel, partials);
    final_k<<<1, 64, 0, stream>>>(partials, out);
}

// Round 11
// 714.461 us; speedup vs baseline: 1.3398x; 1.3398x over previous
//
#include <hip/hip_runtime.h>

#define DDIM 80
#define PLANE 6400
#define VOL 512000
#define HALFV 4
#define NVOL 8
#define NTOT (NVOL*VOL)
#define NCH 20          // float4 chunks per 80-float row
#define RP 84           // padded row floats in rings
#define BLK 256

// ---------------- pair-kernel (2 fused iterations), R9-proven shape ----------------
#define PTY 8           // output rows per tile
#define PCZ 10          // output slices per tile
#define PE1R 12         // E1 rows (y-halo 2 per side)
#define PHR 10          // H1/E2/H2 rows (y-halo 1 per side)
#define PNYT 10         // 80/PTY
#define PNZC 8          // 80/PCZ
#define PGRID (NVOL*PNYT*PNZC)   // 640 blocks; LDS 48.6 KB -> 3 blocks/CU

// ---------------- last-iter kernel (R7 shape) ----------------
#define STY 10
#define SCZ 5
#define SER (STY + 2)
#define SGRID 1024      // 8 vols x 8 yt x 16 zc

__device__ __forceinline__ float4 f4min(float4 a, float4 b) {
    return make_float4(fminf(a.x,b.x), fminf(a.y,b.y), fminf(a.z,b.z), fminf(a.w,b.w));
}
__device__ __forceinline__ float4 f4max(float4 a, float4 b) {
    return make_float4(fmaxf(a.x,b.x), fmaxf(a.y,b.y), fmaxf(a.z,b.z), fmaxf(a.w,b.w));
}
__device__ __forceinline__ int s4(int v){ return (v + 8) & 3; }   // v >= -8
__device__ __forceinline__ int s2(int v){ return (v + 8) & 1; }
__device__ __forceinline__ float updf(float s, float d){ return s + fmaxf(d - s*d, 0.0f); }

// LDS-only barrier (does not drain vmcnt; global prefetches stay in flight)
__device__ __forceinline__ void lbar() {
    asm volatile("s_waitcnt lgkmcnt(0)\n\ts_barrier" ::: "memory");
}

struct EIn { float4 c, zA, zB, yA, yB; float lf, rt; };

// ======================= pair kernel: iters 2j, 2j+1 =======================
// E1 stays LDS-only; skel read+written once per 2 iterations (register ring);
// only e^(2j+2) goes to global. One light barrier per z-step.
template<bool FIRST>
__global__ __launch_bounds__(BLK, 3) void pair_k(const float* __restrict__ xin,
                                                 const float* __restrict__ yin,
                                                 const float* __restrict__ a,
                                                 float* __restrict__ eout,
                                                 float* __restrict__ skel)
{
    __shared__ float E1[4][PE1R][RP];   // 16128 B
    __shared__ float H1[4][PHR][RP];    // 13440 B
    __shared__ float E2[2][PHR][RP];    //  6720 B
    __shared__ float H2[4][PHR][RP];    // 13440 B  (total 49728 B -> 3 blocks/CU)

    const int b = blockIdx.x;
    const int v   = b / (PNYT*PNZC);
    const int rem = b - v*(PNYT*PNZC);
    const int yt  = rem / PNZC;
    const int zci = rem - yt*PNZC;
    const int y0 = yt*PTY;
    const int z0 = zci*PCZ;

    const float* __restrict__ src =
        FIRST ? ((v < HALFV) ? (xin + v*VOL) : (yin + (v-HALFV)*VOL)) : (a + v*VOL);
    float* __restrict__ ev  = eout + v*VOL;
    float* __restrict__ skv = skel + v*VOL;

    const int tid = threadIdx.x;
    const int r = tid / NCH;         // 0..12 (E1 valid r<12, H/E2 r<10, upd r<8)
    const int c = tid - r*NCH;       // 0..19
    const int x4 = 4*c;

    auto loadE1 = [&](int zs, EIn& e) {
        if (r < PE1R) {
            const int gy  = y0 - 2 + r;
            const int gyc = min(max(gy, 0), DDIM-1);
            const int zcl = min(max(zs, 0), DDIM-1);
            const int zm = max(zcl-1, 0), zp = min(zcl+1, DDIM-1);
            const int ym = max(gyc-1, 0), yp = min(gyc+1, DDIM-1);
            const float* rc = src + zcl*PLANE + gyc*DDIM;
            e.c  = *(const float4*)(rc + x4);
            e.lf = rc[max(x4-1, 0)];
            e.rt = rc[min(x4+4, DDIM-1)];
            e.zA = *(const float4*)(src + zm*PLANE + gyc*DDIM + x4);
            e.zB = *(const float4*)(src + zp*PLANE + gyc*DDIM + x4);
            e.yA = *(const float4*)(src + zcl*PLANE + ym*DDIM + x4);
            e.yB = *(const float4*)(src + zcl*PLANE + yp*DDIM + x4);
        }
    };

    auto erodeC = [&](const EIn& e) -> float4 {
        float4 m;
        m.x = fminf(fminf(e.lf,  e.c.x), e.c.y);
        m.y = fminf(fminf(e.c.x, e.c.y), e.c.z);
        m.z = fminf(fminf(e.c.y, e.c.z), e.c.w);
        m.w = fminf(fminf(e.c.z, e.c.w), e.rt);
        return f4min(m, f4min(f4min(e.zA, e.zB), f4min(e.yA, e.yB)));
    };

    auto storeE1 = [&](int zs, float4 m) {
        if (r < PE1R) *(float4*)&E1[s4(zs)][r][x4] = m;
    };

    // H1(zs) row rH (gy=y0-1+rH) = x-window max of E1 row rH+1
    auto hmax1 = [&](int zs) {
        if (r < PHR) {
            const float* row = &E1[s4(zs)][r+1][0];
            const float4 f = *(const float4*)(row + x4);
            const float lf = (c>0)  ? row[x4-1] : f.x;
            const float rt = (c<19) ? row[x4+4] : f.w;
            float4 h;
            h.x = fmaxf(fmaxf(lf,  f.x), f.y);
            h.y = fmaxf(fmaxf(f.x, f.y), f.z);
            h.z = fmaxf(fmaxf(f.y, f.z), f.w);
            h.w = fmaxf(fmaxf(f.z, f.w), rt);
            *(float4*)&H1[s4(zs)][r][x4] = h;
        }
    };

    // E2(zs) = erode(E1) at rows gy=y0-1+r, reading E1 rows r..r+2, slices zs-1..zs+1
    auto erode2 = [&](int zs, bool gw) {
        if (r < PHR) {
            const float* rc = &E1[s4(zs)][r+1][0];
            const float4 cc = *(const float4*)(rc + x4);
            const float lf = (c>0)  ? rc[x4-1] : cc.x;
            const float rt = (c<19) ? rc[x4+4] : cc.w;
            float4 m;
            m.x = fminf(fminf(lf,   cc.x), cc.y);
            m.y = fminf(fminf(cc.x, cc.y), cc.z);
            m.z = fminf(fminf(cc.y, cc.z), cc.w);
            m.w = fminf(fminf(cc.z, cc.w), rt);
            m = f4min(m, *(const float4*)&E1[s4(zs)][r][x4]);       // gy-1
            m = f4min(m, *(const float4*)&E1[s4(zs)][r+2][x4]);     // gy+1
            m = f4min(m, *(const float4*)&E1[s4(zs-1)][r+1][x4]);
            m = f4min(m, *(const float4*)&E1[s4(zs+1)][r+1][x4]);
            *(float4*)&E2[s2(zs)][r][x4] = m;
            if (gw && r >= 1 && r <= PTY)
                *(float4*)(ev + zs*PLANE + (y0-1+r)*DDIM + x4) = m;
        }
    };

    auto hmax2 = [&](int zs) {
        if (r < PHR) {
            const float* row = &E2[s2(zs)][r][0];
            const float4 f = *(const float4*)(row + x4);
            const float lf = (c>0)  ? row[x4-1] : f.x;
            const float rt = (c<19) ? row[x4+4] : f.w;
            float4 h;
            h.x = fmaxf(fmaxf(lf,  f.x), f.y);
            h.y = fmaxf(fmaxf(f.x, f.y), f.z);
            h.z = fmaxf(fmaxf(f.y, f.z), f.w);
            h.w = fmaxf(fmaxf(f.z, f.w), rt);
            *(float4*)&H2[s4(zs)][r][x4] = h;
        }
    };

    auto loadD1 = [&](int z, float4& img, float4& sk) {
        if (r < PTY) {
            const int off = z*PLANE + (y0 + r)*DDIM + x4;
            img = *(const float4*)(src + off);
            if constexpr (!FIRST) sk = *(const float4*)(skv + off);
        }
    };

    EIn eS0, eS1;
    float4 img2N = make_float4(0,0,0,0), img2P = make_float4(0,0,0,0);
    float4 skA = make_float4(0,0,0,0), skB = skA, skC = skA;
    float4 dImg = skA, dSk = skA;

    // ---- prologue ----
    loadE1(z0-2, eS0);
    loadE1(z0-1, eS1);
    storeE1(z0-2, erodeC(eS0));
    storeE1(z0-1, erodeC(eS1));
    loadE1(z0,   eS0);
    loadE1(z0+1, eS1);
    lbar();
    storeE1(z0,   erodeC(eS0));
    storeE1(z0+1, erodeC(eS1));
    hmax1(z0-1);
    loadE1(z0+2, eS1);            // consumed at S=-1 (set1)
    lbar();
    hmax1(z0);
    erode2(z0-1, false);
    loadE1(z0+3, eS0);            // consumed at S=0 (set0)
    lbar();

    // ---- main loop: S = -1 .. PCZ, one light barrier per step ----
#pragma unroll
    for (int S = -1; S <= PCZ; ++S) {
        const int z = z0 + S;
        // ---------- phase A ----------
        if (S <= PCZ-2) {
            const float4 m = erodeC((S & 1) ? eS1 : eS0);
            storeE1(z+3, m);
        }
        if (S <= PCZ-4) loadE1(z+5, (S & 1) ? eS1 : eS0);
        if (S <= PCZ-2) hmax1(z+2);
        if (S <= PCZ-1) erode2(z+1, S <= PCZ-2);
        hmax2(z);
        if (S >= 0 && S <= PCZ-1) {
            if (r < PTY) img2N = *(const float4*)&E1[s4(z)][r+2][x4];
        }
        if (S <= PCZ-2) loadD1(z+1, dImg, dSk);
        lbar();
        // ---------- phase B ----------
        if (S <= PCZ-2) {          // upd1(z+1): iter 2j
            if (r < PTY) {
                float4 dm = make_float4(-1e30f, -1e30f, -1e30f, -1e30f);
#pragma unroll
                for (int s = 0; s < 3; ++s)
#pragma unroll
                    for (int l = 0; l < 3; ++l)
                        dm = f4max(dm, *(const float4*)&H1[s4(z+s)][r + l][x4]);
                float4 dl;
                dl.x = fmaxf(dImg.x - dm.x, 0.0f);
                dl.y = fmaxf(dImg.y - dm.y, 0.0f);
                dl.z = fmaxf(dImg.z - dm.z, 0.0f);
                dl.w = fmaxf(dImg.w - dm.w, 0.0f);
                if constexpr (FIRST) {
                    skC = dl;
                } else {
                    skC.x = updf(dSk.x, dl.x); skC.y = updf(dSk.y, dl.y);
                    skC.z = updf(dSk.z, dl.z); skC.w = updf(dSk.w, dl.w);
                }
            }
        }
        if (S >= 1) {              // upd2(z-1): iter 2j+1
            if (r < PTY) {
                float4 dm = make_float4(-1e30f, -1e30f, -1e30f, -1e30f);
#pragma unroll
                for (int s = 0; s < 3; ++s)
#pragma unroll
                    for (int l = 0; l < 3; ++l)
                        dm = f4max(dm, *(const float4*)&H2[s4(z-2+s)][r + l][x4]);
                float4 dl;
                dl.x = fmaxf(img2P.x - dm.x, 0.0f);
                dl.y = fmaxf(img2P.y - dm.y, 0.0f);
                dl.z = fmaxf(img2P.z - dm.z, 0.0f);
                dl.w = fmaxf(img2P.w - dm.w, 0.0f);
                float4 sf;
                sf.x = updf(skA.x, dl.x); sf.y = updf(skA.y, dl.y);
                sf.z = updf(skA.z, dl.z); sf.w = updf(skA.w, dl.w);
                *(float4*)(skv + (z-1)*PLANE + (y0 + r)*DDIM + x4) = sf;
            }
        }
        skA = skB; skB = skC;
        img2P = img2N;
    }
}

// ============ last iteration (iter 50) fused with the reduction ============
__global__ __launch_bounds__(BLK, 4) void last_k(const float* __restrict__ xin,
                                                 const float* __restrict__ yin,
                                                 const float* __restrict__ a,
                                                 float* __restrict__ skel,
                                                 float* __restrict__ partials)
{
    __shared__ float E[3][SER][RP];
    __shared__ float H[4][SER][RP];
    __shared__ float smm[4][2];

    const int b = blockIdx.x;
    const int v   = b >> 7;          // volume 0..7 (128 blocks each)
    const int rem = b & 127;
    const int yt  = rem >> 4;
    const int zci = rem & 15;
    const int y0 = yt*STY;
    const int z0 = zci*SCZ;

    const float* __restrict__ src = a + v*VOL;
    const float* __restrict__ skv = skel + v*VOL;
    const float* __restrict__ cnt =
        (v < HALFV) ? (yin + v*VOL) : (xin + (v-HALFV)*VOL);

    const int tid = threadIdx.x;
    const int r = tid / NCH;
    const int c = tid - r*NCH;
    const int x4 = 4*c;

    auto slotE = [](int vv){ return (vv + 9) % 3; };

    auto loadE = [&](int zs, EIn& e) {
        if (tid < SER*NCH) {
            const int gy  = y0 - 1 + r;
            const int gyc = min(max(gy, 0), DDIM-1);
            const int zcl = min(max(zs, 0), DDIM-1);
            const int zm = max(zcl-1, 0), zp = min(zcl+1, DDIM-1);
            const int ym = max(gyc-1, 0), yp = min(gyc+1, DDIM-1);
            const float* rc = src + zcl*PLANE + gyc*DDIM;
            e.c  = *(const float4*)(rc + x4);
            e.lf = rc[max(x4-1, 0)];
            e.rt = rc[min(x4+4, DDIM-1)];
            e.zA = *(const float4*)(src + zm*PLANE + gyc*DDIM + x4);
            e.zB = *(const float4*)(src + zp*PLANE + gyc*DDIM + x4);
            e.yA = *(const float4*)(src + zcl*PLANE + ym*DDIM + x4);
            e.yB = *(const float4*)(src + zcl*PLANE + yp*DDIM + x4);
        }
    };
    auto erodeC = [&](const EIn& e) -> float4 {
        float4 m;
        m.x = fminf(fminf(e.lf,  e.c.x), e.c.y);
        m.y = fminf(fminf(e.c.x, e.c.y), e.c.z);
        m.z = fminf(fminf(e.c.y, e.c.z), e.c.w);
        m.w = fminf(fminf(e.c.z, e.c.w), e.rt);
        return f4min(m, f4min(f4min(e.zA, e.zB), f4min(e.yA, e.yB)));
    };
    auto storeE = [&](int zs, const float4& m) {
        if (tid < SER*NCH) *(float4*)&E[slotE(zs)][r][x4] = m;
    };
    auto hmaxStore = [&](int zs, const float4& m) {
        if (tid < SER*NCH) {
            const float* er = &E[slotE(zs)][r][0];
            const float lf = (c > 0)  ? er[x4-1] : m.x;
            const float rt = (c < 19) ? er[x4+4] : m.w;
            float4 h;
            h.x = fmaxf(fmaxf(lf,  m.x), m.y);
            h.y = fmaxf(fmaxf(m.x, m.y), m.z);
            h.z = fmaxf(fmaxf(m.y, m.z), m.w);
            h.w = fmaxf(fmaxf(m.z, m.w), rt);
            *(float4*)&H[s4(zs)][r][x4] = h;
        }
    };
    auto loadD = [&](int z, float4& img, float4& sk, float4& cv) {
        if (tid < STY*NCH) {
            const int off = z*PLANE + (y0 + r)*DDIM + x4;
            img = *(const float4*)(src + off);
            sk  = *(const float4*)(skv + off);
            cv  = *(const float4*)(cnt + off);
        }
    };

    float sa = 0.0f, sb = 0.0f;

    auto dilateUpd = [&](int z, const float4& img, const float4& skin, const float4& cv) {
        if (tid < STY*NCH) {
            float4 dm = make_float4(-1e30f, -1e30f, -1e30f, -1e30f);
#pragma unroll
            for (int s = 0; s < 3; ++s)
#pragma unroll
                for (int l = 0; l < 3; ++l)
                    dm = f4max(dm, *(const float4*)&H[s4(z-1+s)][r + l][x4]);
            float4 dl;
            dl.x = fmaxf(img.x - dm.x, 0.0f);
            dl.y = fmaxf(img.y - dm.y, 0.0f);
            dl.z = fmaxf(img.z - dm.z, 0.0f);
            dl.w = fmaxf(img.w - dm.w, 0.0f);
            float4 s;
            s.x = updf(skin.x, dl.x); s.y = updf(skin.y, dl.y);
            s.z = updf(skin.z, dl.z); s.w = updf(skin.w, dl.w);
            sa += cv.x*s.x + cv.y*s.y + cv.z*s.z + cv.w*s.w;
            sb += s.x + s.y + s.z + s.w;
        }
    };

    EIn eP, eQ, eR;
    float4 m0, m1, m2, mPrev, mNew;
    float4 dImg, dSk, dCv, dImgN, dSkN, dCvN;

    loadE(z0-1, eP);
    loadE(z0,   eQ);
    loadE(z0+1, eR);
    m0 = erodeC(eP);  storeE(z0-1, m0);
    m1 = erodeC(eQ);  storeE(z0,   m1);
    lbar();
    loadE(z0+2, eP);
    loadE(z0+3, eQ);
    hmaxStore(z0-1, m0);
    hmaxStore(z0,   m1);
    m2 = erodeC(eR);  storeE(z0+1, m2);
    loadD(z0, dImg, dSk, dCv);
    lbar();
    mPrev = m2;

#pragma unroll
    for (int S = 0; S < SCZ; ++S) {
        const int z = z0 + S;
        if (S <= SCZ-2) {
            mNew = erodeC((S & 1) ? eQ : eP);
            storeE(z+2, mNew);
        }
        if (S <= SCZ-4) loadE(z+4, (S & 1) ? eQ : eP);
        hmaxStore(z+1, mPrev);
        if (S <= SCZ-2) loadD(z+1, dImgN, dSkN, dCvN);
        lbar();
        dilateUpd(z, dImg, dSk, dCv);
        if (S <= SCZ-2) { mPrev = mNew; dImg = dImgN; dSk = dSkN; dCv = dCvN; }
    }

    // block reduction
    for (int off = 32; off > 0; off >>= 1) {
        sa += __shfl_down(sa, off);
        sb += __shfl_down(sb, off);
    }
    const int wave = tid >> 6;
    if ((tid & 63) == 0) { smm[wave][0] = sa; smm[wave][1] = sb; }
    __syncthreads();
    if (tid == 0) {
        float a0 = 0, a1 = 0;
        for (int w = 0; w < 4; ++w) { a0 += smm[w][0]; a1 += smm[w][1]; }
        partials[b*2 + 0] = a0;
        partials[b*2 + 1] = a1;
    }
}

__global__ void final_k(const float* __restrict__ p, float* __restrict__ out) {
    __shared__ float sums[16];
    const int t = threadIdx.x;
    if (t < 16) {
        const int vv = t >> 1, k = t & 1;
        float acc = 0.0f;
        for (int j = 0; j < 128; ++j) acc += p[(vv*128 + j)*2 + k];
        sums[t] = acc;
    }
    __syncthreads();
    if (t == 0) {
        float acc = 0.0f;
        for (int ch = 0; ch < 4; ++ch) {
            const float tpc     = sums[ch*2 + 0];        // sum clp*y
            const float sum_clp = sums[ch*2 + 1];        // sum clp
            const float tp      = sums[(4+ch)*2 + 0];    // sum x*cll
            const float sum_cll = sums[(4+ch)*2 + 1];    // sum cll
            const float fn  = sum_cll - tp;
            const float fpc = sum_clp - tpc;
            const float clp2voll = (tpc + 1.0f) / (tpc + fpc + 1.0f);
            const float cll2volp = (tp + 1.0f) / (tp + fn + 1.0f);
            acc += 2.0f * clp2voll * cll2volp / (cll2volp + clp2voll + 1e-8f);
        }
        out[0] = 1.0f - acc * 0.25f;
    }
}

extern "C" void kernel_launch(void* const* d_in, const int* in_sizes, int n_in,
                              void* d_out, int out_size, void* d_ws, size_t ws_size,
                              hipStream_t stream) {
    const float* x = (const float*)d_in[0];
    const float* y = (const float*)d_in[1];
    float* out = (float*)d_out;

    float* bufA = (float*)d_ws;
    float* bufB = bufA + NTOT;
    float* skel = bufB + NTOT;
    float* partials = skel + NTOT;   // 2048 floats

    // pair 0: iterations 0,1 (src = inputs) -> bufA holds e^2
    pair_k<true><<<PGRID, BLK, 0, stream>>>(x, y, nullptr, bufA, skel);
    // pairs 1..24: iterations 2j, 2j+1
    for (int j = 1; j <= 24; ++j) {
        float* srcb = (j & 1) ? bufA : bufB;
        float* dstb = (j & 1) ? bufB : bufA;
        pair_k<false><<<PGRID, BLK, 0, stream>>>(nullptr, nullptr, srcb, dstb, skel);
    }
    // iteration 50 fused with reduction (reads e^50 in bufA, skel, counterpart input)
    last_k<<<SGRID, BLK, 0, stream>>>(x, y, bufA, skel, partials);
    final_k<<<1, 64, 0, stream>>>(partials, out);
}

// Round 12
// 711.959 us; speedup vs baseline: 1.3445x; 1.0035x over previous
//
#include <hip/hip_runtime.h>

#define DDIM 80
#define PLANE 6400
#define VOL 512000
#define HALFV 4
#define NVOL 8
#define NTOT (NVOL*VOL)
#define NCH 20          // float4 chunks per 80-float row
#define RP 84           // padded row floats in rings
#define BLK 256

// ---------------- pair-kernel (2 fused iterations), R9-proven shape ----------------
#define PTY 8           // output rows per tile
#define PCZ 10          // output slices per tile
#define PE1R 12         // E1 rows (y-halo 2 per side)
#define PHR 10          // H1/E2/H2 rows (y-halo 1 per side)
#define PNYT 10         // 80/PTY
#define PNZC 8          // 80/PCZ
#define PGRID (NVOL*PNYT*PNZC)   // 640 blocks; LDS 48.6 KB -> 3 blocks/CU

// ---------------- last-iter kernel (R7 shape) ----------------
#define STY 10
#define SCZ 5
#define SER (STY + 2)
#define SGRID 1024      // 8 vols x 8 yt x 16 zc

__device__ __forceinline__ float4 f4min(float4 a, float4 b) {
    return make_float4(fminf(a.x,b.x), fminf(a.y,b.y), fminf(a.z,b.z), fminf(a.w,b.w));
}
__device__ __forceinline__ float4 f4max(float4 a, float4 b) {
    return make_float4(fmaxf(a.x,b.x), fmaxf(a.y,b.y), fmaxf(a.z,b.z), fmaxf(a.w,b.w));
}
__device__ __forceinline__ int s4(int v){ return (v + 8) & 3; }   // v >= -8
__device__ __forceinline__ int s2(int v){ return (v + 8) & 1; }
__device__ __forceinline__ float updf(float s, float d){ return s + fmaxf(d - s*d, 0.0f); }

// LDS-only barrier (does not drain vmcnt; global prefetches stay in flight)
__device__ __forceinline__ void lbar() {
    asm volatile("s_waitcnt lgkmcnt(0)\n\ts_barrier" ::: "memory");
}

struct EIn { float4 c, zA, zB, yA, yB; float lf, rt; };

// ======================= pair kernel: iters 2j, 2j+1 =======================
// XCD-affinity swizzle: v = bid & 7 -> consecutive blockIdx round-robin across
// the 8 XCDs, so each XCD owns ONE volume; its in-flight slab (~3.6 MB) fits
// the 4 MB per-XCD L2, turning halo/stencil re-reads into L2 hits.
template<bool FIRST>
__global__ __launch_bounds__(BLK, 3) void pair_k(const float* __restrict__ xin,
                                                 const float* __restrict__ yin,
                                                 const float* __restrict__ a,
                                                 float* __restrict__ eout,
                                                 float* __restrict__ skel)
{
    __shared__ float E1[4][PE1R][RP];   // 16128 B
    __shared__ float H1[4][PHR][RP];    // 13440 B
    __shared__ float E2[2][PHR][RP];    //  6720 B
    __shared__ float H2[4][PHR][RP];    // 13440 B  (total 49728 B -> 3 blocks/CU)

    const int b = blockIdx.x;
    const int v   = b & 7;           // XCD-affine volume
    const int rem = b >> 3;          // 0..79
    const int yt  = rem / PNZC;      // 0..9
    const int zci = rem - yt*PNZC;   // 0..7
    const int y0 = yt*PTY;
    const int z0 = zci*PCZ;

    const float* __restrict__ src =
        FIRST ? ((v < HALFV) ? (xin + v*VOL) : (yin + (v-HALFV)*VOL)) : (a + v*VOL);
    float* __restrict__ ev  = eout + v*VOL;
    float* __restrict__ skv = skel + v*VOL;

    const int tid = threadIdx.x;
    const int r = tid / NCH;         // 0..12 (E1 valid r<12, H/E2 r<10, upd r<8)
    const int c = tid - r*NCH;       // 0..19
    const int x4 = 4*c;

    auto loadE1 = [&](int zs, EIn& e) {
        if (r < PE1R) {
            const int gy  = y0 - 2 + r;
            const int gyc = min(max(gy, 0), DDIM-1);
            const int zcl = min(max(zs, 0), DDIM-1);
            const int zm = max(zcl-1, 0), zp = min(zcl+1, DDIM-1);
            const int ym = max(gyc-1, 0), yp = min(gyc+1, DDIM-1);
            const float* rc = src + zcl*PLANE + gyc*DDIM;
            e.c  = *(const float4*)(rc + x4);
            e.lf = rc[max(x4-1, 0)];
            e.rt = rc[min(x4+4, DDIM-1)];
            e.zA = *(const float4*)(src + zm*PLANE + gyc*DDIM + x4);
            e.zB = *(const float4*)(src + zp*PLANE + gyc*DDIM + x4);
            e.yA = *(const float4*)(src + zcl*PLANE + ym*DDIM + x4);
            e.yB = *(const float4*)(src + zcl*PLANE + yp*DDIM + x4);
        }
    };

    auto erodeC = [&](const EIn& e) -> float4 {
        float4 m;
        m.x = fminf(fminf(e.lf,  e.c.x), e.c.y);
        m.y = fminf(fminf(e.c.x, e.c.y), e.c.z);
        m.z = fminf(fminf(e.c.y, e.c.z), e.c.w);
        m.w = fminf(fminf(e.c.z, e.c.w), e.rt);
        return f4min(m, f4min(f4min(e.zA, e.zB), f4min(e.yA, e.yB)));
    };

    auto storeE1 = [&](int zs, float4 m) {
        if (r < PE1R) *(float4*)&E1[s4(zs)][r][x4] = m;
    };

    auto hmax1 = [&](int zs) {
        if (r < PHR) {
            const float* row = &E1[s4(zs)][r+1][0];
            const float4 f = *(const float4*)(row + x4);
            const float lf = (c>0)  ? row[x4-1] : f.x;
            const float rt = (c<19) ? row[x4+4] : f.w;
            float4 h;
            h.x = fmaxf(fmaxf(lf,  f.x), f.y);
            h.y = fmaxf(fmaxf(f.x, f.y), f.z);
            h.z = fmaxf(fmaxf(f.y, f.z), f.w);
            h.w = fmaxf(fmaxf(f.z, f.w), rt);
            *(float4*)&H1[s4(zs)][r][x4] = h;
        }
    };

    auto erode2 = [&](int zs, bool gw) {
        if (r < PHR) {
            const float* rc = &E1[s4(zs)][r+1][0];
            const float4 cc = *(const float4*)(rc + x4);
            const float lf = (c>0)  ? rc[x4-1] : cc.x;
            const float rt = (c<19) ? rc[x4+4] : cc.w;
            float4 m;
            m.x = fminf(fminf(lf,   cc.x), cc.y);
            m.y = fminf(fminf(cc.x, cc.y), cc.z);
            m.z = fminf(fminf(cc.y, cc.z), cc.w);
            m.w = fminf(fminf(cc.z, cc.w), rt);
            m = f4min(m, *(const float4*)&E1[s4(zs)][r][x4]);       // gy-1
            m = f4min(m, *(const float4*)&E1[s4(zs)][r+2][x4]);     // gy+1
            m = f4min(m, *(const float4*)&E1[s4(zs-1)][r+1][x4]);
            m = f4min(m, *(const float4*)&E1[s4(zs+1)][r+1][x4]);
            *(float4*)&E2[s2(zs)][r][x4] = m;
            if (gw && r >= 1 && r <= PTY)
                *(float4*)(ev + zs*PLANE + (y0-1+r)*DDIM + x4) = m;
        }
    };

    auto hmax2 = [&](int zs) {
        if (r < PHR) {
            const float* row = &E2[s2(zs)][r][0];
            const float4 f = *(const float4*)(row + x4);
            const float lf = (c>0)  ? row[x4-1] : f.x;
            const float rt = (c<19) ? row[x4+4] : f.w;
            float4 h;
            h.x = fmaxf(fmaxf(lf,  f.x), f.y);
            h.y = fmaxf(fmaxf(f.x, f.y), f.z);
            h.z = fmaxf(fmaxf(f.y, f.z), f.w);
            h.w = fmaxf(fmaxf(f.z, f.w), rt);
            *(float4*)&H2[s4(zs)][r][x4] = h;
        }
    };

    auto loadD1 = [&](int z, float4& img, float4& sk) {
        if (r < PTY) {
            const int off = z*PLANE + (y0 + r)*DDIM + x4;
            img = *(const float4*)(src + off);
            if constexpr (!FIRST) sk = *(const float4*)(skv + off);
        }
    };

    EIn eS0, eS1;
    float4 img2N = make_float4(0,0,0,0), img2P = make_float4(0,0,0,0);
    float4 skA = make_float4(0,0,0,0), skB = skA, skC = skA;
    float4 dImg = skA, dSk = skA;

    // ---- prologue ----
    loadE1(z0-2, eS0);
    loadE1(z0-1, eS1);
    storeE1(z0-2, erodeC(eS0));
    storeE1(z0-1, erodeC(eS1));
    loadE1(z0,   eS0);
    loadE1(z0+1, eS1);
    lbar();
    storeE1(z0,   erodeC(eS0));
    storeE1(z0+1, erodeC(eS1));
    hmax1(z0-1);
    loadE1(z0+2, eS1);            // consumed at S=-1 (set1)
    lbar();
    hmax1(z0);
    erode2(z0-1, false);
    loadE1(z0+3, eS0);            // consumed at S=0 (set0)
    lbar();

    // ---- main loop: S = -1 .. PCZ, one light barrier per step ----
#pragma unroll
    for (int S = -1; S <= PCZ; ++S) {
        const int z = z0 + S;
        // ---------- phase A ----------
        if (S <= PCZ-2) {
            const float4 m = erodeC((S & 1) ? eS1 : eS0);
            storeE1(z+3, m);
        }
        if (S <= PCZ-4) loadE1(z+5, (S & 1) ? eS1 : eS0);
        if (S <= PCZ-2) hmax1(z+2);
        if (S <= PCZ-1) erode2(z+1, S <= PCZ-2);
        hmax2(z);
        if (S >= 0 && S <= PCZ-1) {
            if (r < PTY) img2N = *(const float4*)&E1[s4(z)][r+2][x4];
        }
        if (S <= PCZ-2) loadD1(z+1, dImg, dSk);
        lbar();
        // ---------- phase B ----------
        if (S <= PCZ-2) {          // upd1(z+1): iter 2j
            if (r < PTY) {
                float4 dm = make_float4(-1e30f, -1e30f, -1e30f, -1e30f);
#pragma unroll
                for (int s = 0; s < 3; ++s)
#pragma unroll
                    for (int l = 0; l < 3; ++l)
                        dm = f4max(dm, *(const float4*)&H1[s4(z+s)][r + l][x4]);
                float4 dl;
                dl.x = fmaxf(dImg.x - dm.x, 0.0f);
                dl.y = fmaxf(dImg.y - dm.y, 0.0f);
                dl.z = fmaxf(dImg.z - dm.z, 0.0f);
                dl.w = fmaxf(dImg.w - dm.w, 0.0f);
                if constexpr (FIRST) {
                    skC = dl;
                } else {
                    skC.x = updf(dSk.x, dl.x); skC.y = updf(dSk.y, dl.y);
                    skC.z = updf(dSk.z, dl.z); skC.w = updf(dSk.w, dl.w);
                }
            }
        }
        if (S >= 1) {              // upd2(z-1): iter 2j+1
            if (r < PTY) {
                float4 dm = make_float4(-1e30f, -1e30f, -1e30f, -1e30f);
#pragma unroll
                for (int s = 0; s < 3; ++s)
#pragma unroll
                    for (int l = 0; l < 3; ++l)
                        dm = f4max(dm, *(const float4*)&H2[s4(z-2+s)][r + l][x4]);
                float4 dl;
                dl.x = fmaxf(img2P.x - dm.x, 0.0f);
                dl.y = fmaxf(img2P.y - dm.y, 0.0f);
                dl.z = fmaxf(img2P.z - dm.z, 0.0f);
                dl.w = fmaxf(img2P.w - dm.w, 0.0f);
                float4 sf;
                sf.x = updf(skA.x, dl.x); sf.y = updf(skA.y, dl.y);
                sf.z = updf(skA.z, dl.z); sf.w = updf(skA.w, dl.w);
                *(float4*)(skv + (z-1)*PLANE + (y0 + r)*DDIM + x4) = sf;
            }
        }
        skA = skB; skB = skC;
        img2P = img2N;
    }
}

// ============ last iteration (iter 50) fused with the reduction ============
__global__ __launch_bounds__(BLK, 4) void last_k(const float* __restrict__ xin,
                                                 const float* __restrict__ yin,
                                                 const float* __restrict__ a,
                                                 float* __restrict__ skel,
                                                 float* __restrict__ partials)
{
    __shared__ float E[3][SER][RP];
    __shared__ float H[4][SER][RP];
    __shared__ float smm[4][2];

    const int b = blockIdx.x;
    const int v   = b & 7;           // XCD-affine volume
    const int rem = b >> 3;          // 0..127
    const int yt  = rem >> 4;        // 0..7
    const int zci = rem & 15;        // 0..15
    const int y0 = yt*STY;
    const int z0 = zci*SCZ;

    const float* __restrict__ src = a + v*VOL;
    const float* __restrict__ skv = skel + v*VOL;
    const float* __restrict__ cnt =
        (v < HALFV) ? (yin + v*VOL) : (xin + (v-HALFV)*VOL);

    const int tid = threadIdx.x;
    const int r = tid / NCH;
    const int c = tid - r*NCH;
    const int x4 = 4*c;

    auto slotE = [](int vv){ return (vv + 9) % 3; };

    auto loadE = [&](int zs, EIn& e) {
        if (tid < SER*NCH) {
            const int gy  = y0 - 1 + r;
            const int gyc = min(max(gy, 0), DDIM-1);
            const int zcl = min(max(zs, 0), DDIM-1);
            const int zm = max(zcl-1, 0), zp = min(zcl+1, DDIM-1);
            const int ym = max(gyc-1, 0), yp = min(gyc+1, DDIM-1);
            const float* rc = src + zcl*PLANE + gyc*DDIM;
            e.c  = *(const float4*)(rc + x4);
            e.lf = rc[max(x4-1, 0)];
            e.rt = rc[min(x4+4, DDIM-1)];
            e.zA = *(const float4*)(src + zm*PLANE + gyc*DDIM + x4);
            e.zB = *(const float4*)(src + zp*PLANE + gyc*DDIM + x4);
            e.yA = *(const float4*)(src + zcl*PLANE + ym*DDIM + x4);
            e.yB = *(const float4*)(src + zcl*PLANE + yp*DDIM + x4);
        }
    };
    auto erodeC = [&](const EIn& e) -> float4 {
        float4 m;
        m.x = fminf(fminf(e.lf,  e.c.x), e.c.y);
        m.y = fminf(fminf(e.c.x, e.c.y), e.c.z);
        m.z = fminf(fminf(e.c.y, e.c.z), e.c.w);
        m.w = fminf(fminf(e.c.z, e.c.w), e.rt);
        return f4min(m, f4min(f4min(e.zA, e.zB), f4min(e.yA, e.yB)));
    };
    auto storeE = [&](int zs, const float4& m) {
        if (tid < SER*NCH) *(float4*)&E[slotE(zs)][r][x4] = m;
    };
    auto hmaxStore = [&](int zs, const float4& m) {
        if (tid < SER*NCH) {
            const float* er = &E[slotE(zs)][r][0];
            const float lf = (c > 0)  ? er[x4-1] : m.x;
            const float rt = (c < 19) ? er[x4+4] : m.w;
            float4 h;
            h.x = fmaxf(fmaxf(lf,  m.x), m.y);
            h.y = fmaxf(fmaxf(m.x, m.y), m.z);
            h.z = fmaxf(fmaxf(m.y, m.z), m.w);
            h.w = fmaxf(fmaxf(m.z, m.w), rt);
            *(float4*)&H[s4(zs)][r][x4] = h;
        }
    };
    auto loadD = [&](int z, float4& img, float4& sk, float4& cv) {
        if (tid < STY*NCH) {
            const int off = z*PLANE + (y0 + r)*DDIM + x4;
            img = *(const float4*)(src + off);
            sk  = *(const float4*)(skv + off);
            cv  = *(const float4*)(cnt + off);
        }
    };

    float sa = 0.0f, sb = 0.0f;

    auto dilateUpd = [&](int z, const float4& img, const float4& skin, const float4& cv) {
        if (tid < STY*NCH) {
            float4 dm = make_float4(-1e30f, -1e30f, -1e30f, -1e30f);
#pragma unroll
            for (int s = 0; s < 3; ++s)
#pragma unroll
                for (int l = 0; l < 3; ++l)
                    dm = f4max(dm, *(const float4*)&H[s4(z-1+s)][r + l][x4]);
            float4 dl;
            dl.x = fmaxf(img.x - dm.x, 0.0f);
            dl.y = fmaxf(img.y - dm.y, 0.0f);
            dl.z = fmaxf(img.z - dm.z, 0.0f);
            dl.w = fmaxf(img.w - dm.w, 0.0f);
            float4 s;
            s.x = updf(skin.x, dl.x); s.y = updf(skin.y, dl.y);
            s.z = updf(skin.z, dl.z); s.w = updf(skin.w, dl.w);
            sa += cv.x*s.x + cv.y*s.y + cv.z*s.z + cv.w*s.w;
            sb += s.x + s.y + s.z + s.w;
        }
    };

    EIn eP, eQ, eR;
    float4 m0, m1, m2, mPrev, mNew;
    float4 dImg, dSk, dCv, dImgN, dSkN, dCvN;

    loadE(z0-1, eP);
    loadE(z0,   eQ);
    loadE(z0+1, eR);
    m0 = erodeC(eP);  storeE(z0-1, m0);
    m1 = erodeC(eQ);  storeE(z0,   m1);
    lbar();
    loadE(z0+2, eP);
    loadE(z0+3, eQ);
    hmaxStore(z0-1, m0);
    hmaxStore(z0,   m1);
    m2 = erodeC(eR);  storeE(z0+1, m2);
    loadD(z0, dImg, dSk, dCv);
    lbar();
    mPrev = m2;

#pragma unroll
    for (int S = 0; S < SCZ; ++S) {
        const int z = z0 + S;
        if (S <= SCZ-2) {
            mNew = erodeC((S & 1) ? eQ : eP);
            storeE(z+2, mNew);
        }
        if (S <= SCZ-4) loadE(z+4, (S & 1) ? eQ : eP);
        hmaxStore(z+1, mPrev);
        if (S <= SCZ-2) loadD(z+1, dImgN, dSkN, dCvN);
        lbar();
        dilateUpd(z, dImg, dSk, dCv);
        if (S <= SCZ-2) { mPrev = mNew; dImg = dImgN; dSk = dSkN; dCv = dCvN; }
    }

    // block reduction
    for (int off = 32; off > 0; off >>= 1) {
        sa += __shfl_down(sa, off);
        sb += __shfl_down(sb, off);
    }
    const int wave = tid >> 6;
    if ((tid & 63) == 0) { smm[wave][0] = sa; smm[wave][1] = sb; }
    __syncthreads();
    if (tid == 0) {
        float a0 = 0, a1 = 0;
        for (int w = 0; w < 4; ++w) { a0 += smm[w][0]; a1 += smm[w][1]; }
        partials[b*2 + 0] = a0;
        partials[b*2 + 1] = a1;
    }
}

__global__ void final_k(const float* __restrict__ p, float* __restrict__ out) {
    __shared__ float sums[16];
    const int t = threadIdx.x;
    if (t < 16) {
        const int vv = t >> 1, k = t & 1;
        float acc = 0.0f;
        // partials indexed by b = rem*? -> v = b&7; sum all b with b&7 == vv
        for (int j = 0; j < 128; ++j) acc += p[((j << 3) | vv)*2 + k];
        sums[t] = acc;
    }
    __syncthreads();
    if (t == 0) {
        float acc = 0.0f;
        for (int ch = 0; ch < 4; ++ch) {
            const float tpc     = sums[ch*2 + 0];        // sum clp*y
            const float sum_clp = sums[ch*2 + 1];        // sum clp
            const float tp      = sums[(4+ch)*2 + 0];    // sum x*cll
            const float sum_cll = sums[(4+ch)*2 + 1];    // sum cll
            const float fn  = sum_cll - tp;
            const float fpc = sum_clp - tpc;
            const float clp2voll = (tpc + 1.0f) / (tpc + fpc + 1.0f);
            const float cll2volp = (tp + 1.0f) / (tp + fn + 1.0f);
            acc += 2.0f * clp2voll * cll2volp / (cll2volp + clp2voll + 1e-8f);
        }
        out[0] = 1.0f - acc * 0.25f;
    }
}

extern "C" void kernel_launch(void* const* d_in, const int* in_sizes, int n_in,
                              void* d_out, int out_size, void* d_ws, size_t ws_size,
                              hipStream_t stream) {
    const float* x = (const float*)d_in[0];
    const float* y = (const float*)d_in[1];
    float* out = (float*)d_out;

    float* bufA = (float*)d_ws;
    float* bufB = bufA + NTOT;
    float* skel = bufB + NTOT;
    float* partials = skel + NTOT;   // 2048 floats

    // pair 0: iterations 0,1 (src = inputs) -> bufA holds e^2
    pair_k<true><<<PGRID, BLK, 0, stream>>>(x, y, nullptr, bufA, skel);
    // pairs 1..24: iterations 2j, 2j+1
    for (int j = 1; j <= 24; ++j) {
        float* srcb = (j & 1) ? bufA : bufB;
        float* dstb = (j & 1) ? bufB : bufA;
        pair_k<false><<<PGRID, BLK, 0, stream>>>(nullptr, nullptr, srcb, dstb, skel);
    }
    // iteration 50 fused with reduction (reads e^50 in bufA, skel, counterpart input)
    last_k<<<SGRID, BLK, 0, stream>>>(x, y, bufA, skel, partials);
    final_k<<<1, 64, 0, stream>>>(partials, out);
}